// Round 9
// baseline (38.734 us; speedup 1.0000x reference)
//
#include <hip/hip_runtime.h>

#define NP   4096      // P = 64*64 pixels per image
#define NIMG 8
#define NK   21
#define ROWH 32        // halves per packed row (64 B)
#define NT   16        // 256-row supertiles per image
#define ITEMS_PER_IMG 136               // triangular (I,J) supertile pairs, J>=I
#define N_ITEMS (NIMG * ITEMS_PER_IMG)  // 1088
#define N_SLOTS (N_ITEMS * 2)           // 2176 blocks: one per (item, j-half)

// sqrt(0.5 * log2(e)): pre-scale features so exponent = -sum((fi-fj)^2), w = exp2(exponent)
#define FEAT_SCALE 0.84932180028801907f

typedef _Float16 half8 __attribute__((ext_vector_type(8)));
typedef float f32x4 __attribute__((ext_vector_type(4)));

__device__ __forceinline__ unsigned short h2u(_Float16 h) {
  union { _Float16 f; unsigned short u; } c; c.f = h; return c.u;
}

__device__ __forceinline__ void resize_w(int o, float* w, int* t) {
  // jax.image.resize bilinear antialias=True, 128->64 (verified exact rounds 1-8)
  const float ww[4] = {0.25f, 0.75f, 0.75f, 0.25f};
  float s = 0.f;
  #pragma unroll
  for (int a = 0; a < 4; ++a) {
    int tap = 2 * o - 1 + a;
    bool v = (tap >= 0) && (tap < 128);
    w[a] = v ? ww[a] : 0.f;
    t[a] = v ? tap : 0;
    s += w[a];
  }
  float inv = 1.f / s;
  #pragma unroll
  for (int a = 0; a < 4; ++a) w[a] *= inv;
}

// 896 blocks = (n, oyg, kq): kq in [0,7) handles 3 seg channels; kq==0 also does features.
__global__ void __launch_bounds__(256) prep_kernel(const float* __restrict__ images,
                                                   const float* __restrict__ segs,
                                                   _Float16* __restrict__ distA,
                                                   _Float16* __restrict__ distB,
                                                   _Float16* __restrict__ segh) {
  int bid = blockIdx.x;
  int tid = threadIdx.x;
  int n = bid / 112;
  int r112 = bid % 112;
  int oyg = r112 / 7, kq = r112 % 7;
  int ox = tid & 63, oyl = tid >> 6;
  int oy = oyg * 4 + oyl;
  int p = oy * 64 + ox;
  int idx = n * NP + p;

  if (kq == 0) {
    // ---- bilateral features -> distA/distB rows (identical math to rounds 2-8) ----
    const float cxy  = FEAT_SCALE / 50.0f;   // sigma_xy * scale = 50
    const float crgb = FEAT_SCALE / 15.0f;   // sigma_rgb = 15
    const float* img = images + (size_t)n * 3 * NP;
    float f[5];
    f[0] = (float)ox * cxy;
    f[1] = (float)oy * cxy;
    f[2] = img[0 * NP + p] * crgb;
    f[3] = img[1 * NP + p] * crgb;
    f[4] = img[2 * NP + p] * crgb;

    _Float16 ah[5], al[5];
    float n2 = 0.f;
    #pragma unroll
    for (int d = 0; d < 5; ++d) {
      ah[d] = (_Float16)f[d];
      float rem = f[d] - (float)ah[d];
      al[d] = (_Float16)rem;
      float at = (float)ah[d] + (float)al[d];
      n2 = fmaf(at, at, n2);
    }
    _Float16 nh = (_Float16)n2;
    _Float16 nl = (_Float16)(n2 - (float)nh);

    _Float16 rowA[ROWH], rowB[ROWH];
    #pragma unroll
    for (int q = 0; q < ROWH; ++q) { rowA[q] = (_Float16)0.f; rowB[q] = (_Float16)0.f; }
    #pragma unroll
    for (int d = 0; d < 5; ++d) {
      rowA[d]      = ah[d];
      rowA[5 + d]  = al[d];
      rowA[10 + d] = ah[d];
      rowB[d]      = (_Float16)2.f * ah[d];
      rowB[5 + d]  = (_Float16)2.f * ah[d];
      rowB[10 + d] = (_Float16)2.f * al[d];
    }
    rowA[15] = nh;  rowA[16] = nl;  rowA[17] = (_Float16)1.f; rowA[18] = (_Float16)1.f;
    rowB[15] = (_Float16)-1.f; rowB[16] = (_Float16)-1.f; rowB[17] = -nh; rowB[18] = -nl;

    half8* oA = (half8*)(distA + (size_t)idx * ROWH);
    half8* oB = (half8*)(distB + (size_t)idx * ROWH);
    #pragma unroll
    for (int q = 0; q < 4; ++q) {
      oA[q] = ((half8*)rowA)[q];
      oB[q] = ((half8*)rowB)[q];
    }
  }

  // ---- seg resize, channels kq*3 .. kq*3+2, double-buffered LDS slab ----
  __shared__ float slab[2][10][128];
  int r0 = 8 * oyg - 1;
  float wy[4], wx[4]; int ty[4], tx[4];
  resize_w(oy, wy, ty);                    // ty unused: rel row = 2*oyl+ay
  resize_w(ox, wx, tx);

  int lofs[5], lrr[5], lcc[5];
  #pragma unroll
  for (int q = 0; q < 5; ++q) {
    int e = tid + q * 256;
    int rr = e >> 7, cc = e & 127;
    int row = r0 + rr;
    row = row < 0 ? 0 : (row > 127 ? 127 : row);   // clamp; invalid taps weight 0
    lofs[q] = row * 128 + cc;
    lrr[q] = rr; lcc[q] = cc;
  }

  const float* sb = segs + (size_t)n * NK * 128 * 128;
  float rg[5];
  {
    const float* sk = sb + (size_t)(kq * 3) * 128 * 128;
    #pragma unroll
    for (int q = 0; q < 5; ++q) rg[q] = sk[lofs[q]];
    #pragma unroll
    for (int q = 0; q < 5; ++q) slab[0][lrr[q]][lcc[q]] = rg[q];
  }

  float outk[3];
  #pragma unroll
  for (int kk = 0; kk < 3; ++kk) {
    if (kk < 2) {                          // issue next channel's loads early
      const float* sk = sb + (size_t)(kq * 3 + kk + 1) * 128 * 128;
      #pragma unroll
      for (int q = 0; q < 5; ++q) rg[q] = sk[lofs[q]];
    }
    __syncthreads();                       // slab[kk&1] writes visible
    float a = 0.f;
    #pragma unroll
    for (int ay = 0; ay < 4; ++ay) {
      int rel = 2 * oyl + ay;
      float rsum = 0.f;
      #pragma unroll
      for (int ax = 0; ax < 4; ++ax) rsum = fmaf(wx[ax], slab[kk & 1][rel][tx[ax]], rsum);
      a = fmaf(wy[ay], rsum, a);
    }
    outk[kk] = a;
    if (kk < 2) {
      #pragma unroll
      for (int q = 0; q < 5; ++q) slab[(kk & 1) ^ 1][lrr[q]][lcc[q]] = rg[q];
    }
  }

  char* rowp = (char*)(segh + (size_t)idx * ROWH);
  #pragma unroll
  for (int kk = 0; kk < 3; ++kk)
    *(unsigned short*)(rowp + 6 * kq + 2 * kk) = h2u((_Float16)outk[kk]);
  if (kq == 6) {                           // zero pad halves 21..31 (bytes 42..63)
    *(unsigned short*)    (rowp + 42) = 0;
    *(unsigned int*)      (rowp + 44) = 0u;
    *(unsigned long long*)(rowp + 48) = 0ull;
    *(unsigned long long*)(rowp + 56) = 0ull;
  }
}

// Block = (n, I, J, h): one j-half (128 rows) staged in 16 KB LDS (granule-SoA).
// 8 blocks/CU co-resident -> 32 waves/CU. PURE kernel: no atomics, no fences;
// partial sum plain-stored to slots[bid].
__global__ void __launch_bounds__(256, 8) crf_mfma(const _Float16* __restrict__ distA,
                                                   const _Float16* __restrict__ distB,
                                                   const _Float16* __restrict__ segh,
                                                   float* __restrict__ slots) {
  __shared__ char lds[16384];              // [2 arrays][4 granules][128 rows][16B]
  int bid = blockIdx.x;
  int item = bid >> 1, h = bid & 1;
  int n = item / ITEMS_PER_IMG;
  int rem = item % ITEMS_PER_IMG;
  int I = 0;
  while (rem >= NT - I) { rem -= NT - I; ++I; }
  int J = I + rem;

  int tid = threadIdx.x;
  int lane = tid & 63, wid = tid >> 6;
  int r = lane & 15, g4 = lane >> 4;

  const char* dA = (const char*)(distA + (size_t)n * NP * ROWH);
  const char* dB = (const char*)(distB + (size_t)n * NP * ROWH);
  const char* sg = (const char*)(segh  + (size_t)n * NP * ROWH);

  // stage B half-chunk (128 rows): coalesced global -> LDS granule-SoA
  {
    const char* srcBd = dB + (size_t)(J * 256 + h * 128) * 64;
    const char* srcBs = sg + (size_t)(J * 256 + h * 128) * 64;
    #pragma unroll
    for (int q = 0; q < 2; ++q) {
      int e = tid + q * 256;               // e = row*4 + g
      float4 vd = *(const float4*)(srcBd + e * 16);
      float4 vs = *(const float4*)(srcBs + e * 16);
      int dof = (e & 3) * 2048 + (e >> 2) * 16;
      *(float4*)(lds + dof) = vd;
      *(float4*)(lds + 8192 + dof) = vs;
    }
  }

  // A fragments: this wave's 4 i-tiles (coalesced, L2/L3-resident)
  half8 Ad[4], As[4];
  #pragma unroll
  for (int m = 0; m < 4; ++m) {
    size_t aoff = (size_t)(I * 256 + (wid * 4 + m) * 16 + r) * 64 + g4 * 16;
    Ad[m] = *(const half8*)(dA + aoff);
    As[m] = *(const half8*)(sg + aoff);
  }
  __syncthreads();

  f32x4 zero = {0.f, 0.f, 0.f, 0.f};
  float sm0 = 0.f, sm1 = 0.f, sm2 = 0.f, sm3 = 0.f;
  float sum;

  if (J > I) {                             // all tiles weight 2
    const char* bp0 = lds + g4 * 2048 + r * 16;
    half8 Bd = *(const half8*)bp0;
    half8 Bs = *(const half8*)(bp0 + 8192);
    #pragma unroll 4
    for (int jt = 0; jt < 8; ++jt) {
      int jn = (jt < 7) ? jt + 1 : jt;     // prefetch next j-tile from LDS
      const char* bp = lds + g4 * 2048 + (jn * 16 + r) * 16;
      half8 nBd = *(const half8*)bp;
      half8 nBs = *(const half8*)(bp + 8192);
      #pragma unroll
      for (int m = 0; m < 4; ++m) {
        f32x4 ad  = __builtin_amdgcn_mfma_f32_16x16x32_f16(Ad[m], Bd, zero, 0, 0, 0);
        f32x4 as_ = __builtin_amdgcn_mfma_f32_16x16x32_f16(As[m], Bs, zero, 0, 0, 0);
        float t0 = fmaf(__builtin_amdgcn_exp2f(ad[0]), as_[0],
                   fmaf(__builtin_amdgcn_exp2f(ad[1]), as_[1], 0.f));
        float t1 = fmaf(__builtin_amdgcn_exp2f(ad[2]), as_[2],
                   fmaf(__builtin_amdgcn_exp2f(ad[3]), as_[3], 0.f));
        float t = t0 + t1;
        if (m == 0) sm0 += t; else if (m == 1) sm1 += t;
        else if (m == 2) sm2 += t; else sm3 += t;
      }
      Bd = nBd; Bs = nBs;
    }
    sum = 2.f * (sm0 + sm1 + sm2 + sm3);
  } else {                                 // diagonal: per-tile weight {0,1,2}
    #pragma unroll 2
    for (int jt = 0; jt < 8; ++jt) {
      int jta = I * 16 + h * 8 + jt;
      const char* bp = lds + g4 * 2048 + (jt * 16 + r) * 16;
      half8 Bd = *(const half8*)bp;
      half8 Bs = *(const half8*)(bp + 8192);
      #pragma unroll
      for (int m = 0; m < 4; ++m) {
        int it = I * 16 + wid * 4 + m;
        if (jta >= it) {                   // wave-uniform skip of zero-weight tiles
          float s = (jta > it) ? 2.f : 1.f;
          f32x4 ad  = __builtin_amdgcn_mfma_f32_16x16x32_f16(Ad[m], Bd, zero, 0, 0, 0);
          f32x4 as_ = __builtin_amdgcn_mfma_f32_16x16x32_f16(As[m], Bs, zero, 0, 0, 0);
          float t0 = fmaf(__builtin_amdgcn_exp2f(ad[0]), as_[0],
                     fmaf(__builtin_amdgcn_exp2f(ad[1]), as_[1], 0.f));
          float t1 = fmaf(__builtin_amdgcn_exp2f(ad[2]), as_[2],
                     fmaf(__builtin_amdgcn_exp2f(ad[3]), as_[3], 0.f));
          float t = s * (t0 + t1);
          if (m == 0) sm0 += t; else if (m == 1) sm1 += t;
          else if (m == 2) sm2 += t; else sm3 += t;
        }
      }
    }
    sum = sm0 + sm1 + sm2 + sm3;
  }

  // block reduction (reuse staging LDS after sync) -> plain store to slots
  #pragma unroll
  for (int off = 32; off > 0; off >>= 1) sum += __shfl_down(sum, off);
  __syncthreads();                         // all LDS B-reads done
  float* red = (float*)lds;
  if (lane == 0) red[wid] = sum;
  __syncthreads();
  if (tid == 0) slots[bid] = red[0] + red[1] + red[2] + red[3];
}

// 1 block: deterministic fixed-order f64 reduce of the 2176 partials.
__global__ void __launch_bounds__(256) reduce_kernel(const float* __restrict__ slots,
                                                     float* __restrict__ out) {
  __shared__ double dred[4];
  int tid = threadIdx.x;
  int lane = tid & 63, wid = tid >> 6;
  double s = 0.0;
  #pragma unroll
  for (int q = 0; q < 9; ++q) {
    int k = tid + q * 256;
    if (k < N_SLOTS) s += (double)slots[k];
  }
  #pragma unroll
  for (int off = 32; off > 0; off >>= 1) s += __shfl_down(s, off);
  if (lane == 0) dred[wid] = s;
  __syncthreads();
  if (tid == 0) {
    double tot = dred[0] + dred[1] + dred[2] + dred[3];
    out[0] = (float)(tot * (-1e-8 / 8.0));  // WEIGHT * (-sum/N)
  }
}

extern "C" void kernel_launch(void* const* d_in, const int* in_sizes, int n_in,
                              void* d_out, int out_size, void* d_ws, size_t ws_size,
                              hipStream_t stream) {
  const float* images = (const float*)d_in[0];   // [8,3,64,64]
  const float* segs   = (const float*)d_in[1];   // [8,21,128,128]
  float* out  = (float*)d_out;
  float* slots = (float*)d_ws;                                   // 8.7 KB
  _Float16* distA = (_Float16*)((char*)d_ws + 16384);            // 2 MB
  _Float16* distB = distA + (size_t)NIMG * NP * ROWH;            // 2 MB
  _Float16* segh  = distB + (size_t)NIMG * NP * ROWH;            // 2 MB

  hipLaunchKernelGGL(prep_kernel, dim3(NIMG * 16 * 7), dim3(256), 0, stream,
                     images, segs, distA, distB, segh);
  hipLaunchKernelGGL(crf_mfma, dim3(N_SLOTS), dim3(256), 0, stream,
                     distA, distB, segh, slots);
  hipLaunchKernelGGL(reduce_kernel, dim3(1), dim3(256), 0, stream, slots, out);
}

// Round 10
// 33.144 us; speedup vs baseline: 1.1687x; 1.1687x over previous
//
#include <hip/hip_runtime.h>

#define NP   4096      // P = 64*64 pixels per image
#define NIMG 8
#define NK   21
#define ROWH 32        // halves per packed row (64 B)
#define NT   16        // 256-row supertiles per image
#define ITEMS_PER_IMG 136               // triangular (I,J) supertile pairs, J>=I
#define N_HALF (NIMG * ITEMS_PER_IMG * 2)   // 2176 half-items (item, j-half)
#define GRID2 1024                      // persistent blocks: 2-3 half-items each
// LDS geometry: granule stride 2064 (=2048+16 pad, kills 4-way write conflict),
// array stride 4*2064=8256, buffer stride 2*8256=16512, total 2*16512=33024.
#define GSTRIDE 2064
#define ASTRIDE 8256
#define BUFSTRIDE 16512

// sqrt(0.5 * log2(e)): pre-scale features so exponent = -sum((fi-fj)^2), w = exp2(exponent)
#define FEAT_SCALE 0.84932180028801907f

typedef _Float16 half8 __attribute__((ext_vector_type(8)));
typedef float f32x4 __attribute__((ext_vector_type(4)));

__device__ __forceinline__ unsigned short h2u(_Float16 h) {
  union { _Float16 f; unsigned short u; } c; c.f = h; return c.u;
}

__device__ __forceinline__ void resize_w(int o, float* w, int* t) {
  // jax.image.resize bilinear antialias=True, 128->64 (verified exact rounds 1-9)
  const float ww[4] = {0.25f, 0.75f, 0.75f, 0.25f};
  float s = 0.f;
  #pragma unroll
  for (int a = 0; a < 4; ++a) {
    int tap = 2 * o - 1 + a;
    bool v = (tap >= 0) && (tap < 128);
    w[a] = v ? ww[a] : 0.f;
    t[a] = v ? tap : 0;
    s += w[a];
  }
  float inv = 1.f / s;
  #pragma unroll
  for (int a = 0; a < 4; ++a) w[a] *= inv;
}

// 896 blocks = (n, oyg, kq): kq in [0,7) handles 3 seg channels; kq==0 also does features.
__global__ void __launch_bounds__(256) prep_kernel(const float* __restrict__ images,
                                                   const float* __restrict__ segs,
                                                   _Float16* __restrict__ distA,
                                                   _Float16* __restrict__ distB,
                                                   _Float16* __restrict__ segh) {
  int bid = blockIdx.x;
  int tid = threadIdx.x;
  int n = bid / 112;
  int r112 = bid % 112;
  int oyg = r112 / 7, kq = r112 % 7;
  int ox = tid & 63, oyl = tid >> 6;
  int oy = oyg * 4 + oyl;
  int p = oy * 64 + ox;
  int idx = n * NP + p;

  if (kq == 0) {
    // ---- bilateral features -> distA/distB rows (identical math to rounds 2-9) ----
    const float cxy  = FEAT_SCALE / 50.0f;   // sigma_xy * scale = 50
    const float crgb = FEAT_SCALE / 15.0f;   // sigma_rgb = 15
    const float* img = images + (size_t)n * 3 * NP;
    float f[5];
    f[0] = (float)ox * cxy;
    f[1] = (float)oy * cxy;
    f[2] = img[0 * NP + p] * crgb;
    f[3] = img[1 * NP + p] * crgb;
    f[4] = img[2 * NP + p] * crgb;

    _Float16 ah[5], al[5];
    float n2 = 0.f;
    #pragma unroll
    for (int d = 0; d < 5; ++d) {
      ah[d] = (_Float16)f[d];
      float rem = f[d] - (float)ah[d];
      al[d] = (_Float16)rem;
      float at = (float)ah[d] + (float)al[d];
      n2 = fmaf(at, at, n2);
    }
    _Float16 nh = (_Float16)n2;
    _Float16 nl = (_Float16)(n2 - (float)nh);

    _Float16 rowA[ROWH], rowB[ROWH];
    #pragma unroll
    for (int q = 0; q < ROWH; ++q) { rowA[q] = (_Float16)0.f; rowB[q] = (_Float16)0.f; }
    #pragma unroll
    for (int d = 0; d < 5; ++d) {
      rowA[d]      = ah[d];
      rowA[5 + d]  = al[d];
      rowA[10 + d] = ah[d];
      rowB[d]      = (_Float16)2.f * ah[d];
      rowB[5 + d]  = (_Float16)2.f * ah[d];
      rowB[10 + d] = (_Float16)2.f * al[d];
    }
    rowA[15] = nh;  rowA[16] = nl;  rowA[17] = (_Float16)1.f; rowA[18] = (_Float16)1.f;
    rowB[15] = (_Float16)-1.f; rowB[16] = (_Float16)-1.f; rowB[17] = -nh; rowB[18] = -nl;

    half8* oA = (half8*)(distA + (size_t)idx * ROWH);
    half8* oB = (half8*)(distB + (size_t)idx * ROWH);
    #pragma unroll
    for (int q = 0; q < 4; ++q) {
      oA[q] = ((half8*)rowA)[q];
      oB[q] = ((half8*)rowB)[q];
    }
  }

  // ---- seg resize, channels kq*3 .. kq*3+2, double-buffered LDS slab ----
  __shared__ float slab[2][10][128];
  int r0 = 8 * oyg - 1;
  float wy[4], wx[4]; int ty[4], tx[4];
  resize_w(oy, wy, ty);                    // ty unused: rel row = 2*oyl+ay
  resize_w(ox, wx, tx);

  int lofs[5], lrr[5], lcc[5];
  #pragma unroll
  for (int q = 0; q < 5; ++q) {
    int e = tid + q * 256;
    int rr = e >> 7, cc = e & 127;
    int row = r0 + rr;
    row = row < 0 ? 0 : (row > 127 ? 127 : row);   // clamp; invalid taps weight 0
    lofs[q] = row * 128 + cc;
    lrr[q] = rr; lcc[q] = cc;
  }

  const float* sb = segs + (size_t)n * NK * 128 * 128;
  float rg[5];
  {
    const float* sk = sb + (size_t)(kq * 3) * 128 * 128;
    #pragma unroll
    for (int q = 0; q < 5; ++q) rg[q] = sk[lofs[q]];
    #pragma unroll
    for (int q = 0; q < 5; ++q) slab[0][lrr[q]][lcc[q]] = rg[q];
  }

  float outk[3];
  #pragma unroll
  for (int kk = 0; kk < 3; ++kk) {
    if (kk < 2) {                          // issue next channel's loads early
      const float* sk = sb + (size_t)(kq * 3 + kk + 1) * 128 * 128;
      #pragma unroll
      for (int q = 0; q < 5; ++q) rg[q] = sk[lofs[q]];
    }
    __syncthreads();                       // slab[kk&1] writes visible
    float a = 0.f;
    #pragma unroll
    for (int ay = 0; ay < 4; ++ay) {
      int rel = 2 * oyl + ay;
      float rsum = 0.f;
      #pragma unroll
      for (int ax = 0; ax < 4; ++ax) rsum = fmaf(wx[ax], slab[kk & 1][rel][tx[ax]], rsum);
      a = fmaf(wy[ay], rsum, a);
    }
    outk[kk] = a;
    if (kk < 2) {
      #pragma unroll
      for (int q = 0; q < 5; ++q) slab[(kk & 1) ^ 1][lrr[q]][lcc[q]] = rg[q];
    }
  }

  char* rowp = (char*)(segh + (size_t)idx * ROWH);
  #pragma unroll
  for (int kk = 0; kk < 3; ++kk)
    *(unsigned short*)(rowp + 6 * kq + 2 * kk) = h2u((_Float16)outk[kk]);
  if (kq == 6) {                           // zero pad halves 21..31 (bytes 42..63)
    *(unsigned short*)    (rowp + 42) = 0;
    *(unsigned int*)      (rowp + 44) = 0u;
    *(unsigned long long*)(rowp + 48) = 0ull;
    *(unsigned long long*)(rowp + 56) = 0ull;
  }
}

__device__ __forceinline__ void decode_item(int item, int& n, int& I, int& J, int& h) {
  h = item & 1;
  int pr = item >> 1;
  n = pr / ITEMS_PER_IMG;
  int rem = pr - n * ITEMS_PER_IMG;
  int I_ = 0;
  while (rem >= NT - I_) { rem -= NT - I_; ++I_; }
  I = I_;
  J = I_ + rem;
}

// Persistent blocks: each processes half-items bid, bid+1024, (bid+2048 if <2176)
// with double-buffered LDS staging: next item's global loads issued before the
// sync, written to the alternate buffer after compute. PURE: no atomics/fences.
__global__ void __launch_bounds__(256, 4) crf_mfma(const _Float16* __restrict__ distA,
                                                   const _Float16* __restrict__ distB,
                                                   const _Float16* __restrict__ segh,
                                                   float* __restrict__ slots) {
  __shared__ char lds[2 * BUFSTRIDE];      // 33 KB: [buf][array][granule pad 2064]
  __shared__ float red[4];
  int bid = blockIdx.x;
  int tid = threadIdx.x;
  int lane = tid & 63, wid = tid >> 6;
  int r = lane & 15, g4 = lane >> 4;

  int item = bid;
  int n, I, J, h;
  decode_item(item, n, I, J, h);

  float4 rd0, rd1, rs0, rs1;
  {
    const char* srcBd = (const char*)(distB + (size_t)n * NP * ROWH) + (size_t)(J * 256 + h * 128) * 64;
    const char* srcBs = (const char*)(segh  + (size_t)n * NP * ROWH) + (size_t)(J * 256 + h * 128) * 64;
    rd0 = *(const float4*)(srcBd + tid * 16);
    rd1 = *(const float4*)(srcBd + tid * 16 + 4096);
    rs0 = *(const float4*)(srcBs + tid * 16);
    rs1 = *(const float4*)(srcBs + tid * 16 + 4096);
  }
  {
    int e0 = tid, e1 = tid + 256;
    int d0 = (e0 & 3) * GSTRIDE + (e0 >> 2) * 16;
    int d1 = (e1 & 3) * GSTRIDE + (e1 >> 2) * 16;
    *(float4*)(lds + d0) = rd0;
    *(float4*)(lds + d1) = rd1;
    *(float4*)(lds + ASTRIDE + d0) = rs0;
    *(float4*)(lds + ASTRIDE + d1) = rs1;
  }

  float blocksum = 0.f;
  int cur = 0;
  f32x4 zero = {0.f, 0.f, 0.f, 0.f};

  #pragma unroll 1
  for (;;) {
    int nxt = item + GRID2;
    bool more = (nxt < N_HALF);
    int nn = 0, nI = 0, nJ = 0, nh = 0;

    // current item's A fragments (global, L2-hot): issue before sync
    const char* dAn = (const char*)(distA + (size_t)n * NP * ROWH);
    const char* sgn = (const char*)(segh  + (size_t)n * NP * ROWH);
    half8 Ad[4], As[4];
    #pragma unroll
    for (int m = 0; m < 4; ++m) {
      size_t aoff = (size_t)(I * 256 + (wid * 4 + m) * 16 + r) * 64 + g4 * 16;
      Ad[m] = *(const half8*)(dAn + aoff);
      As[m] = *(const half8*)(sgn + aoff);
    }

    if (more) {                            // issue next item's staging loads early
      decode_item(nxt, nn, nI, nJ, nh);
      const char* srcBd = (const char*)(distB + (size_t)nn * NP * ROWH) + (size_t)(nJ * 256 + nh * 128) * 64;
      const char* srcBs = (const char*)(segh  + (size_t)nn * NP * ROWH) + (size_t)(nJ * 256 + nh * 128) * 64;
      rd0 = *(const float4*)(srcBd + tid * 16);
      rd1 = *(const float4*)(srcBd + tid * 16 + 4096);
      rs0 = *(const float4*)(srcBs + tid * 16);
      rs1 = *(const float4*)(srcBs + tid * 16 + 4096);
    }

    __syncthreads();                       // lds[cur] staged & visible

    const char* buf = lds + cur * BUFSTRIDE;
    float sm0 = 0.f, sm1 = 0.f, sm2 = 0.f, sm3 = 0.f;

    if (J > I) {                           // all tiles weight 2
      #pragma unroll 4
      for (int jt = 0; jt < 8; ++jt) {
        const char* bp = buf + g4 * GSTRIDE + (jt * 16 + r) * 16;
        half8 Bd = *(const half8*)bp;
        half8 Bs = *(const half8*)(bp + ASTRIDE);
        #pragma unroll
        for (int m = 0; m < 4; ++m) {
          f32x4 ad  = __builtin_amdgcn_mfma_f32_16x16x32_f16(Ad[m], Bd, zero, 0, 0, 0);
          f32x4 as_ = __builtin_amdgcn_mfma_f32_16x16x32_f16(As[m], Bs, zero, 0, 0, 0);
          float t0 = fmaf(__builtin_amdgcn_exp2f(ad[0]), as_[0],
                     fmaf(__builtin_amdgcn_exp2f(ad[1]), as_[1], 0.f));
          float t1 = fmaf(__builtin_amdgcn_exp2f(ad[2]), as_[2],
                     fmaf(__builtin_amdgcn_exp2f(ad[3]), as_[3], 0.f));
          float t = 2.f * (t0 + t1);
          if (m == 0) sm0 += t; else if (m == 1) sm1 += t;
          else if (m == 2) sm2 += t; else sm3 += t;
        }
      }
    } else {                               // diagonal: per-tile weight {0,1,2}
      #pragma unroll 2
      for (int jt = 0; jt < 8; ++jt) {
        int jta = I * 16 + h * 8 + jt;
        const char* bp = buf + g4 * GSTRIDE + (jt * 16 + r) * 16;
        half8 Bd = *(const half8*)bp;
        half8 Bs = *(const half8*)(bp + ASTRIDE);
        #pragma unroll
        for (int m = 0; m < 4; ++m) {
          int it = I * 16 + wid * 4 + m;
          if (jta >= it) {                 // wave-uniform skip of zero-weight tiles
            float s = (jta > it) ? 2.f : 1.f;
            f32x4 ad  = __builtin_amdgcn_mfma_f32_16x16x32_f16(Ad[m], Bd, zero, 0, 0, 0);
            f32x4 as_ = __builtin_amdgcn_mfma_f32_16x16x32_f16(As[m], Bs, zero, 0, 0, 0);
            float t0 = fmaf(__builtin_amdgcn_exp2f(ad[0]), as_[0],
                       fmaf(__builtin_amdgcn_exp2f(ad[1]), as_[1], 0.f));
            float t1 = fmaf(__builtin_amdgcn_exp2f(ad[2]), as_[2],
                       fmaf(__builtin_amdgcn_exp2f(ad[3]), as_[3], 0.f));
            float t = s * (t0 + t1);
            if (m == 0) sm0 += t; else if (m == 1) sm1 += t;
            else if (m == 2) sm2 += t; else sm3 += t;
          }
        }
      }
    }
    blocksum += sm0 + sm1 + sm2 + sm3;

    if (!more) break;

    // write next item's chunk to the alternate buffer (no sync needed: other
    // waves only read lds[cur]; next iteration's sync publishes these writes)
    {
      char* nbuf = lds + (cur ^ 1) * BUFSTRIDE;
      int e0 = tid, e1 = tid + 256;
      int d0 = (e0 & 3) * GSTRIDE + (e0 >> 2) * 16;
      int d1 = (e1 & 3) * GSTRIDE + (e1 >> 2) * 16;
      *(float4*)(nbuf + d0) = rd0;
      *(float4*)(nbuf + d1) = rd1;
      *(float4*)(nbuf + ASTRIDE + d0) = rs0;
      *(float4*)(nbuf + ASTRIDE + d1) = rs1;
    }
    item = nxt; n = nn; I = nI; J = nJ; h = nh; cur ^= 1;
  }

  // block reduction -> plain store to slots[bid]
  #pragma unroll
  for (int off = 32; off > 0; off >>= 1) blocksum += __shfl_down(blocksum, off);
  if (lane == 0) red[wid] = blocksum;
  __syncthreads();
  if (tid == 0) slots[bid] = red[0] + red[1] + red[2] + red[3];
}

// 1 block: deterministic fixed-order f64 reduce of the 1024 partials.
__global__ void __launch_bounds__(256) reduce_kernel(const float* __restrict__ slots,
                                                     float* __restrict__ out) {
  __shared__ double dred[4];
  int tid = threadIdx.x;
  int lane = tid & 63, wid = tid >> 6;
  double s = 0.0;
  #pragma unroll
  for (int q = 0; q < 4; ++q) s += (double)slots[tid + q * 256];
  #pragma unroll
  for (int off = 32; off > 0; off >>= 1) s += __shfl_down(s, off);
  if (lane == 0) dred[wid] = s;
  __syncthreads();
  if (tid == 0) {
    double tot = dred[0] + dred[1] + dred[2] + dred[3];
    out[0] = (float)(tot * (-1e-8 / 8.0));  // WEIGHT * (-sum/N)
  }
}

extern "C" void kernel_launch(void* const* d_in, const int* in_sizes, int n_in,
                              void* d_out, int out_size, void* d_ws, size_t ws_size,
                              hipStream_t stream) {
  const float* images = (const float*)d_in[0];   // [8,3,64,64]
  const float* segs   = (const float*)d_in[1];   // [8,21,128,128]
  float* out  = (float*)d_out;
  float* slots = (float*)d_ws;                                   // 4 KB
  _Float16* distA = (_Float16*)((char*)d_ws + 16384);            // 2 MB
  _Float16* distB = distA + (size_t)NIMG * NP * ROWH;            // 2 MB
  _Float16* segh  = distB + (size_t)NIMG * NP * ROWH;            // 2 MB

  hipLaunchKernelGGL(prep_kernel, dim3(NIMG * 16 * 7), dim3(256), 0, stream,
                     images, segs, distA, distB, segh);
  hipLaunchKernelGGL(crf_mfma, dim3(GRID2), dim3(256), 0, stream,
                     distA, distB, segh, slots);
  hipLaunchKernelGGL(reduce_kernel, dim3(1), dim3(256), 0, stream, slots, out);
}